// Round 8
// baseline (318.862 us; speedup 1.0000x reference)
//
#include <hip/hip_runtime.h>
#include <hip/hip_bf16.h>

// Problem constants (B=2,S=2048 -> T=4096 tokens), H=1024, F=512, E=8, top-2.
#define T_TOK    4096
#define H_DIM    1024
#define F_DIM    512
#define N_EXP    8
#define N_ASSIGN 8192          // T_TOK * 2
#define BM 128
#define BN 128
#define BK 64
#define MAX_TILES 80
#define GRID_MT   71           // worst-case sum_e ceil(Ne/128) = 64 + 7
#define TRU      3072          // transpose units: 2048 (Wg/Wu) + 1024 (Wd), 64x64 tiles

typedef __bf16 bf16x8 __attribute__((ext_vector_type(8)));
typedef float  f32x4  __attribute__((ext_vector_type(4)));

#define MFMA16(a, b, c) __builtin_amdgcn_mfma_f32_16x16x32_bf16((a), (b), (c), 0, 0, 0)

// Async global->LDS, 16B per lane. LDS dest = wave-uniform base + lane*16.
__device__ __forceinline__ void gl_lds16(const __bf16* g, __bf16* l) {
    __builtin_amdgcn_global_load_lds(
        (const __attribute__((address_space(1))) unsigned int*)g,
        (__attribute__((address_space(3))) unsigned int*)l,
        16, 0, 0);
}

// ---------------------------------------------------------------------------
// Transpose: fp32 -> bf16, K-contiguous layouts, 64x64 tiles, bf16x8 stores.
//   z<8 : Wg[h][f] -> Wcat[e][p_g(f)][h]   p_g(f) = (f>>4)*32 + (f&15)
//   z<16: Wu[h][f] -> Wcat[e][p_u(f)][h]   p_u(f) = p_g(f) + 16
//   else: Wd[f][h] -> Wdt [e][h][f]
// VERBATIM R12.
// ---------------------------------------------------------------------------
__global__ __launch_bounds__(256) void transpose_kernel(
    const float* __restrict__ Wg, const float* __restrict__ Wu, const float* __restrict__ Wd,
    __bf16* __restrict__ Wcat, __bf16* __restrict__ Wdt)
{
    __shared__ float tile[64][65];     // 16.9 KB
    int b = blockIdx.x, tid = threadIdx.x;
    const float* src; int C, z, c0, r0;
    if (b < 2048) {                // Wg/Wu: R=1024, C=512 -> 16x8 tiles/z
        z = b >> 7; int rem = b & 127;
        c0 = (rem & 7) * 64; r0 = (rem >> 3) * 64;
        src = (z < 8) ? Wg + (size_t)z * H_DIM * F_DIM
                      : Wu + (size_t)(z - 8) * H_DIM * F_DIM;
        C = F_DIM;
    } else {                       // Wd: R=512, C=1024 -> 8x16 tiles/z
        int v = b - 2048; z = 16 + (v >> 7); int rem = v & 127;
        c0 = (rem & 15) * 64; r0 = (rem >> 4) * 64;
        src = Wd + (size_t)(z - 16) * F_DIM * H_DIM;
        C = H_DIM;
    }
    int fr = tid >> 4, f4 = tid & 15;          // 16 rows/pass, 16 float4/row
#pragma unroll
    for (int p = 0; p < 4; ++p) {
        int row = p * 16 + fr;
        float4 v = *(const float4*)(src + (size_t)(r0 + row) * C + c0 + f4 * 4);
        tile[row][f4 * 4 + 0] = v.x; tile[row][f4 * 4 + 1] = v.y;
        tile[row][f4 * 4 + 2] = v.z; tile[row][f4 * 4 + 3] = v.w;
    }
    __syncthreads();
    int j = tid & 7, cl = tid >> 3;            // chunk-of-8-rows, 32 cols/pass
#pragma unroll
    for (int p = 0; p < 2; ++p) {
        int c = cl + p * 32;
        bf16x8 v;
#pragma unroll
        for (int i = 0; i < 8; ++i) v[i] = (__bf16)tile[8 * j + i][c];
        if (z < 16) {
            int e = (z < 8) ? z : z - 8;
            int sel = (z < 8) ? 0 : 16;
            int f = c0 + c;
            int pp = ((f >> 4) << 5) + (f & 15) + sel;
            *(bf16x8*)&Wcat[(size_t)e * 2 * F_DIM * H_DIM + (size_t)pp * H_DIM + r0 + 8 * j] = v;
        } else {
            *(bf16x8*)&Wdt[(size_t)(z - 16) * H_DIM * F_DIM + (size_t)(c0 + c) * F_DIM + r0 + 8 * j] = v;
        }
    }
}

// ---------------------------------------------------------------------------
// Routing: 1 wave = 1 token, Wr staged in LDS as [e][h^(e<<2)]. VERBATIM R12.
// ---------------------------------------------------------------------------
__global__ __launch_bounds__(256) void routing_kernel(
    const float* __restrict__ x, const float* __restrict__ Wr,
    __bf16* __restrict__ xb, int* __restrict__ top_e, float* __restrict__ top_w)
{
    __shared__ float WrS[N_EXP * H_DIM];   // [e][h^(e<<2)], 32 KB
    int tid = threadIdx.x;
    for (int i = tid; i < N_EXP * H_DIM; i += 256) {
        int h = i >> 3, e = i & 7;         // global Wr is [h][e]
        WrS[e * H_DIM + (h ^ (e << 2))] = Wr[i];
    }
    __syncthreads();

    int wave = tid >> 6, lane = tid & 63;
    int t = blockIdx.x * 4 + wave;
    const float* xrow = x + (size_t)t * H_DIM;
    __bf16* xbrow = xb + (size_t)t * H_DIM;

    float part[N_EXP];
#pragma unroll
    for (int e = 0; e < N_EXP; ++e) part[e] = 0.f;
#pragma unroll 4
    for (int s = 0; s < 16; ++s) {
        int h = s * 64 + lane;
        float xs = xrow[h];
        xbrow[h] = (__bf16)xs;
#pragma unroll
        for (int e = 0; e < N_EXP; ++e) part[e] += xs * WrS[e * H_DIM + (h ^ (e << 2))];
    }
#pragma unroll
    for (int m = 1; m < 64; m <<= 1) {
#pragma unroll
        for (int e = 0; e < N_EXP; ++e) part[e] += __shfl_xor(part[e], m, 64);
    }
    if (lane == 0) {
        float v1 = -1e30f, v2 = -1e30f;
        int i1 = 0, i2 = 0;
#pragma unroll
        for (int e = 0; e < N_EXP; ++e) {
            float p = part[e];
            if (p > v1)      { v2 = v1; i2 = i1; v1 = p; i1 = e; }
            else if (p > v2) { v2 = p;  i2 = e; }
        }
        float w1 = 1.f / (1.f + __expf(v2 - v1));   // normalized top-2; softmax denom cancels
        top_e[t * 2]     = i1;  top_e[t * 2 + 1] = i2;
        top_w[t * 2]     = w1;  top_w[t * 2 + 1] = 1.f - w1;
    }
}

// ---------------------------------------------------------------------------
// sort (8 blocks): R12 + zero the rdy flag array (read by the fused GEMM
// kernel; kernel boundary makes the zeros visible device-wide).
// ---------------------------------------------------------------------------
__global__ __launch_bounds__(256) void sort_kernel(
    const int* __restrict__ top_e, const float* __restrict__ top_w,
    int* __restrict__ perm, float* __restrict__ wts, int* __restrict__ tokslot,
    int* __restrict__ tile_e, int* __restrict__ tile_m0, int* __restrict__ tile_cnt,
    int* __restrict__ n_tiles, int* __restrict__ rdy)
{
    __shared__ int hist[N_EXP][256];
    __shared__ int ebase[N_EXP];
    int tid = threadIdx.x, myexp = blockIdx.x;
    if (myexp == 0 && tid < MAX_TILES) rdy[tid] = 0;
    int c[N_EXP];
#pragma unroll
    for (int e = 0; e < N_EXP; ++e) c[e] = 0;
#pragma unroll 4
    for (int i = 0; i < 32; ++i) {
        int ee = top_e[i * 256 + tid];
#pragma unroll
        for (int e = 0; e < N_EXP; ++e) c[e] += (ee == e);
    }
#pragma unroll
    for (int e = 0; e < N_EXP; ++e) hist[e][tid] = c[e];
    __syncthreads();
    for (int s = 1; s < 256; s <<= 1) {
        int v[N_EXP];
#pragma unroll
        for (int e = 0; e < N_EXP; ++e) v[e] = (tid >= s) ? hist[e][tid - s] : 0;
        __syncthreads();
#pragma unroll
        for (int e = 0; e < N_EXP; ++e) hist[e][tid] += v[e];
        __syncthreads();
    }
    if (tid == 0) {
        int o = 0, nt = 0;
        for (int e = 0; e < N_EXP; ++e) {
            ebase[e] = o;
            int ne = hist[e][255];
            if (myexp == 0) {
                for (int m0 = 0; m0 < ne; m0 += BM) {
                    tile_e[nt]   = e;
                    tile_m0[nt]  = o + m0;
                    tile_cnt[nt] = (ne - m0 < BM) ? (ne - m0) : BM;
                    ++nt;
                }
            }
            o += ne;
        }
        if (myexp == 0) *n_tiles = nt;
    }
    __syncthreads();
    int base = ebase[myexp] + hist[myexp][tid] - c[myexp];
#pragma unroll 4
    for (int i = 0; i < 32; ++i) {
        int a = i * 256 + tid;
        if (top_e[a] == myexp) {
            perm[base]   = a >> 1;
            wts[base]    = top_w[a];
            tokslot[a]   = base;
            ++base;
        }
    }
}

// ---------------------------------------------------------------------------
// R17: FUSED gateup+down. Phase 1 = R12 gateup verbatim; per-mt ready flag
// (release: threadfence+atomicAdd); Phase 2 = R12 down verbatim for the SAME
// (mt,n0), gated on rdy[mt]==8 (relaxed spin + acquire threadfence).
// Why safe: grid 568 <= capacity 768 (33KB LDS -> 4/CU; launch_bounds(256,3)
// -> 3/CU guaranteed), and every block signals BEFORE any wait -> all flags
// reach 8 regardless of scheduling; no circular dependency. act producer and
// consumer share an XCD (same nat swizzle) so data flows through XCD-local
// L2; fences handle the formal cross-XCD visibility requirement (G16).
// Why: down(mt,n0) only needs mt's 8 gateup tiles -- the kernel-boundary
// version pays a full 568-block drain + node gap instead (~8-15us).
// GEMM inner loops UNTOUCHED (R11/13/14/15 schedule probes all lost).
// ---------------------------------------------------------------------------
__global__ __launch_bounds__(256, 3) void fused_gemm_kernel(
    const __bf16* __restrict__ xb, const __bf16* __restrict__ Wcat,
    const __bf16* __restrict__ Wdt,
    const int* __restrict__ perm, const float* __restrict__ wts,
    const int* __restrict__ tile_e, const int* __restrict__ tile_m0, const int* __restrict__ tile_cnt,
    const int* __restrict__ n_tiles, __bf16* __restrict__ act,
    __bf16* __restrict__ P, int* __restrict__ rdy)
{
    int nat = (blockIdx.x & 7) * GRID_MT + (blockIdx.x >> 3);   // XCD-chunked
    int mt = nat >> 3;
    if (mt >= *n_tiles) return;
    int e = tile_e[mt], m0 = tile_m0[mt], mcnt = tile_cnt[mt];
    int n0 = (nat & 7) * BN;
    __shared__ __align__(16) __bf16 As[BM * BK];
    __shared__ __align__(16) __bf16 Bs[BN * BK];
    __shared__ int   rowtok[BM];
    __shared__ float roww[BM];
    int tid = threadIdx.x;
    if (tid < BM) {
        int slot = m0 + ((tid < mcnt) ? tid : 0);
        rowtok[tid] = perm[slot];
        roww[tid]   = wts[slot];
    }
    __syncthreads();
    int wave = tid >> 6, lane = tid & 63;
    int srow   = wave * 8 + (lane >> 3);
    int schunk = (((lane & 7) ^ ((lane >> 3) & 7))) * 8;
    int wm = wave & 1, wn = wave >> 1;
    int quad = lane >> 4, l16 = lane & 15;
    __bf16* aLds = As + wave * 512;
    __bf16* bLds = Bs + wave * 512;

    // ---------------- Phase 1: gate+up (N packed = 1024) -------------------
    {
        const __bf16* We = Wcat + (size_t)e * (2 * F_DIM) * H_DIM;
        const __bf16* aptr[4];
        const __bf16* bptr[4];
#pragma unroll
        for (int j = 0; j < 4; ++j) {
            int r = j * 32 + srow;
            aptr[j] = xb + (size_t)rowtok[r] * H_DIM + schunk;
            bptr[j] = We + (size_t)(n0 + r) * H_DIM + schunk;
        }
        f32x4 acc[4][4];
#pragma unroll
        for (int a = 0; a < 4; ++a)
#pragma unroll
            for (int b = 0; b < 4; ++b) acc[a][b] = (f32x4){0.f, 0.f, 0.f, 0.f};
        for (int k0 = 0; k0 < H_DIM; k0 += BK) {
#pragma unroll
            for (int j = 0; j < 4; ++j) {
                gl_lds16(aptr[j] + k0, aLds + j * 2048);
                gl_lds16(bptr[j] + k0, bLds + j * 2048);
            }
            __syncthreads();
#pragma unroll
            for (int s = 0; s < 2; ++s) {
                int sw = (((quad + s * 4) ^ (l16 & 7))) * 8;
                bf16x8 af[4], bf[4];
#pragma unroll
                for (int im = 0; im < 4; ++im)
                    af[im] = *(const bf16x8*)&As[(wm * 64 + im * 16 + l16) * 64 + sw];
#pragma unroll
                for (int in = 0; in < 4; ++in)
                    bf[in] = *(const bf16x8*)&Bs[(wn * 64 + in * 16 + l16) * 64 + sw];
#pragma unroll
                for (int im = 0; im < 4; ++im)
#pragma unroll
                    for (int in = 0; in < 4; ++in)
                        acc[im][in] = MFMA16(af[im], bf[in], acc[im][in]);
            }
            __syncthreads();
        }
        int fbase = (n0 >> 1) + wn * 32;
#pragma unroll
        for (int im = 0; im < 4; ++im) {
#pragma unroll
            for (int ip = 0; ip < 2; ++ip) {
                f32x4 g = acc[im][ip * 2], u = acc[im][ip * 2 + 1];
                int fcol = fbase + ip * 16 + l16;
#pragma unroll
                for (int r = 0; r < 4; ++r) {
                    int rl = wm * 64 + im * 16 + quad * 4 + r;
                    if (rl < mcnt) {
                        float gv = g[r], uv = u[r];
                        float sg = gv / (1.f + __expf(-gv));
                        act[(size_t)(m0 + rl) * F_DIM + fcol] = (__bf16)(sg * uv * roww[rl]);
                    }
                }
            }
        }
    }

    // ---------------- publish: this (mt, n0) slice of act is done ----------
    __threadfence();                       // agent-scope release of act stores
    __syncthreads();
    if (tid == 0)
        __hip_atomic_fetch_add(&rdy[mt], 1, __ATOMIC_RELAXED,
                               __HIP_MEMORY_SCOPE_AGENT);

    // ---------------- wait: all 8 n-slices of mt's act rows ----------------
    if (tid == 0) {
        while (__hip_atomic_load(&rdy[mt], __ATOMIC_RELAXED,
                                 __HIP_MEMORY_SCOPE_AGENT) < 8)
            __builtin_amdgcn_s_sleep(2);
    }
    __syncthreads();
    __threadfence();                       // acquire: drop stale act lines

    // ---------------- Phase 2: down-proj (N = H = 1024) --------------------
    {
        const __bf16* Wd_e = Wdt + (size_t)e * H_DIM * F_DIM;
        const __bf16* aptr[4];
        const __bf16* bptr[4];
#pragma unroll
        for (int j = 0; j < 4; ++j) {
            int r = j * 32 + srow;
            int ar = m0 + ((r < mcnt) ? r : 0);
            aptr[j] = act  + (size_t)ar * F_DIM + schunk;
            bptr[j] = Wd_e + (size_t)(n0 + r) * F_DIM + schunk;
        }
        f32x4 acc[4][4];
#pragma unroll
        for (int a = 0; a < 4; ++a)
#pragma unroll
            for (int b = 0; b < 4; ++b) acc[a][b] = (f32x4){0.f, 0.f, 0.f, 0.f};
        for (int k0 = 0; k0 < F_DIM; k0 += BK) {
#pragma unroll
            for (int j = 0; j < 4; ++j) {
                gl_lds16(aptr[j] + k0, aLds + j * 2048);
                gl_lds16(bptr[j] + k0, bLds + j * 2048);
            }
            __syncthreads();
#pragma unroll
            for (int s = 0; s < 2; ++s) {
                int sw = (((quad + s * 4) ^ (l16 & 7))) * 8;
                bf16x8 af[4], bf[4];
#pragma unroll
                for (int im = 0; im < 4; ++im)
                    af[im] = *(const bf16x8*)&As[(wm * 64 + im * 16 + l16) * 64 + sw];
#pragma unroll
                for (int in = 0; in < 4; ++in)
                    bf[in] = *(const bf16x8*)&Bs[(wn * 64 + in * 16 + l16) * 64 + sw];
#pragma unroll
                for (int im = 0; im < 4; ++im)
#pragma unroll
                    for (int in = 0; in < 4; ++in)
                        acc[im][in] = MFMA16(af[im], bf[in], acc[im][in]);
            }
            __syncthreads();
        }
#pragma unroll
        for (int im = 0; im < 4; ++im) {
#pragma unroll
            for (int in = 0; in < 4; ++in) {
                int col = n0 + wn * 64 + in * 16 + l16;
#pragma unroll
                for (int r = 0; r < 4; ++r) {
                    int rl = wm * 64 + im * 16 + quad * 4 + r;
                    if (rl < mcnt)
                        P[(size_t)(m0 + rl) * H_DIM + col] = (__bf16)acc[im][in][r];
                }
            }
        }
    }
}

// ---------------------------------------------------------------------------
// Combine: out[t] = P[slot1(t)] + P[slot2(t)] (fp32 accumulate). 1 wave/token,
// bf16x8 loads, f32x4 stores. VERBATIM R12.
// ---------------------------------------------------------------------------
__global__ __launch_bounds__(256) void combine_kernel(
    const __bf16* __restrict__ P, const int* __restrict__ tokslot,
    float* __restrict__ out)
{
    int wave = threadIdx.x >> 6, lane = threadIdx.x & 63;
    int t = blockIdx.x * 4 + wave;
    int s1 = tokslot[2 * t], s2 = tokslot[2 * t + 1];
    const bf16x8* p1 = (const bf16x8*)(P + (size_t)s1 * H_DIM);
    const bf16x8* p2 = (const bf16x8*)(P + (size_t)s2 * H_DIM);
    float* o = out + (size_t)t * H_DIM;
#pragma unroll
    for (int i = 0; i < 2; ++i) {
        int idx = i * 64 + lane;
        bf16x8 a = p1[idx], b = p2[idx];
        f32x4 lo, hi;
#pragma unroll
        for (int j = 0; j < 4; ++j) lo[j] = (float)a[j] + (float)b[j];
#pragma unroll
        for (int j = 0; j < 4; ++j) hi[j] = (float)a[4 + j] + (float)b[4 + j];
        *(f32x4*)(o + idx * 8)     = lo;
        *(f32x4*)(o + idx * 8 + 4) = hi;
    }
}

// ---------------------------------------------------------------------------
extern "C" void kernel_launch(void* const* d_in, const int* in_sizes, int n_in,
                              void* d_out, int out_size, void* d_ws, size_t ws_size,
                              hipStream_t stream)
{
    const float* x  = (const float*)d_in[0];
    const float* Wr = (const float*)d_in[1];
    const float* Wg = (const float*)d_in[2];
    const float* Wu = (const float*)d_in[3];
    const float* Wd = (const float*)d_in[4];
    float* out = (float*)d_out;

    char* ws = (char*)d_ws;
    size_t off = 0;
    auto carve = [&](size_t bytes) {
        char* p = ws + off;
        off = (off + bytes + 255) & ~(size_t)255;
        return p;
    };
    __bf16* xb   = (__bf16*)carve((size_t)T_TOK * H_DIM * 2);                 // 8 MB
    __bf16* Wcat = (__bf16*)carve((size_t)N_EXP * 2 * F_DIM * H_DIM * 2);     // 16 MB
    __bf16* Wdt  = (__bf16*)carve((size_t)N_EXP * H_DIM * F_DIM * 2);         // 8 MB
    __bf16* act  = (__bf16*)carve((size_t)N_ASSIGN * F_DIM * 2);              // 8 MB
    __bf16* P    = (__bf16*)carve((size_t)N_ASSIGN * H_DIM * 2);              // 16 MB
    int*   top_e = (int*)carve((size_t)T_TOK * 2 * sizeof(int));
    float* top_w = (float*)carve((size_t)T_TOK * 2 * sizeof(float));
    int*   perm  = (int*)carve((size_t)N_ASSIGN * sizeof(int));
    float* wts   = (float*)carve((size_t)N_ASSIGN * sizeof(float));
    int*  tokslot= (int*)carve((size_t)N_ASSIGN * sizeof(int));
    int*   tl_e  = (int*)carve(MAX_TILES * sizeof(int));
    int*   tl_m0 = (int*)carve(MAX_TILES * sizeof(int));
    int*   tl_cn = (int*)carve(MAX_TILES * sizeof(int));
    int*   n_til = (int*)carve(sizeof(int));
    int*   rdy   = (int*)carve(MAX_TILES * sizeof(int));

    transpose_kernel<<<TRU, 256, 0, stream>>>(Wg, Wu, Wd, Wcat, Wdt);
    routing_kernel<<<T_TOK / 4, 256, 0, stream>>>(x, Wr, xb, top_e, top_w);
    sort_kernel<<<N_EXP, 256, 0, stream>>>(
        top_e, top_w, perm, wts, tokslot, tl_e, tl_m0, tl_cn, n_til, rdy);
    fused_gemm_kernel<<<GRID_MT * 8, 256, 0, stream>>>(
        xb, Wcat, Wdt, perm, wts, tl_e, tl_m0, tl_cn, n_til, act, P, rdy);
    combine_kernel<<<T_TOK / 4, 256, 0, stream>>>(P, tokslot, out);
}

// Round 9
// 181.326 us; speedup vs baseline: 1.7585x; 1.7585x over previous
//
#include <hip/hip_runtime.h>
#include <hip/hip_bf16.h>

// Problem constants (B=2,S=2048 -> T=4096 tokens), H=1024, F=512, E=8, top-2.
#define T_TOK    4096
#define H_DIM    1024
#define F_DIM    512
#define N_EXP    8
#define N_ASSIGN 8192          // T_TOK * 2
#define BM 128
#define BN 128
#define BK 64
#define MAX_TILES 80
#define GRID_MT   71           // worst-case sum_e ceil(Ne/128) = 64 + 7
#define ROUTE_BLKS 1024        // T_TOK / 4
#define TRU      3072          // transpose units: 2048 (Wg/Wu) + 1024 (Wd)

typedef __bf16 bf16x8 __attribute__((ext_vector_type(8)));
typedef float  f32x4  __attribute__((ext_vector_type(4)));

#define MFMA16(a, b, c) __builtin_amdgcn_mfma_f32_16x16x32_bf16((a), (b), (c), 0, 0, 0)

// Async global->LDS, 16B per lane. LDS dest = wave-uniform base + lane*16.
__device__ __forceinline__ void gl_lds16(const __bf16* g, __bf16* l) {
    __builtin_amdgcn_global_load_lds(
        (const __attribute__((address_space(1))) unsigned int*)g,
        (__attribute__((address_space(3))) unsigned int*)l,
        16, 0, 0);
}

// ---------------------------------------------------------------------------
// R18 prep: routing (blocks 0..1023) UNION transpose (blocks 1024..4095) in
// one launch. Both phase bodies are VERBATIM R12; branch is block-uniform so
// __syncthreads inside each path is safe. LDS = 32KB union (WrS 32K/tile
// 16.6K). Saves one launch boundary; prior session measured the merge as a
// no-op-or-better. R17 lesson: in-kernel producer/consumer fences destroy
// XCD L2 (fused GEMM 188us vs 55) -- kernel boundaries are the cheap sync.
// ---------------------------------------------------------------------------
__global__ __launch_bounds__(256) void prep_kernel(
    const float* __restrict__ Wg, const float* __restrict__ Wu, const float* __restrict__ Wd,
    __bf16* __restrict__ Wcat, __bf16* __restrict__ Wdt,
    const float* __restrict__ x, const float* __restrict__ Wr,
    __bf16* __restrict__ xb, int* __restrict__ top_e, float* __restrict__ top_w)
{
    __shared__ __align__(16) char smem[32768];
    int b = blockIdx.x, tid = threadIdx.x;

    if (b < ROUTE_BLKS) {
        // ---------------- routing: tokens 4b..4b+3 (R12 verbatim) ----------
        float* WrS = (float*)smem;                 // [e][h^(e<<2)], 32 KB
        for (int i = tid; i < N_EXP * H_DIM; i += 256) {
            int h = i >> 3, e = i & 7;             // global Wr is [h][e]
            WrS[e * H_DIM + (h ^ (e << 2))] = Wr[i];
        }
        __syncthreads();

        int wave = tid >> 6, lane = tid & 63;
        int t = b * 4 + wave;
        const float* xrow = x + (size_t)t * H_DIM;
        __bf16* xbrow = xb + (size_t)t * H_DIM;

        float part[N_EXP];
#pragma unroll
        for (int e = 0; e < N_EXP; ++e) part[e] = 0.f;
#pragma unroll 4
        for (int s = 0; s < 16; ++s) {
            int h = s * 64 + lane;
            float xs = xrow[h];
            xbrow[h] = (__bf16)xs;
#pragma unroll
            for (int e = 0; e < N_EXP; ++e) part[e] += xs * WrS[e * H_DIM + (h ^ (e << 2))];
        }
#pragma unroll
        for (int m = 1; m < 64; m <<= 1) {
#pragma unroll
            for (int e = 0; e < N_EXP; ++e) part[e] += __shfl_xor(part[e], m, 64);
        }
        if (lane == 0) {
            float v1 = -1e30f, v2 = -1e30f;
            int i1 = 0, i2 = 0;
#pragma unroll
            for (int e = 0; e < N_EXP; ++e) {
                float p = part[e];
                if (p > v1)      { v2 = v1; i2 = i1; v1 = p; i1 = e; }
                else if (p > v2) { v2 = p;  i2 = e; }
            }
            float w1 = 1.f / (1.f + __expf(v2 - v1));   // normalized top-2
            top_e[t * 2]     = i1;  top_e[t * 2 + 1] = i2;
            top_w[t * 2]     = w1;  top_w[t * 2 + 1] = 1.f - w1;
        }
    } else {
        // ---------------- transpose unit v (R12 verbatim) ------------------
        float (*tile)[65] = (float (*)[65])smem;   // 16.6 KB of the union
        int v = b - ROUTE_BLKS;
        const float* src; int C, z, c0, r0;
        if (v < 2048) {                // Wg/Wu: R=1024, C=512 -> 16x8 tiles/z
            z = v >> 7; int rem = v & 127;
            c0 = (rem & 7) * 64; r0 = (rem >> 3) * 64;
            src = (z < 8) ? Wg + (size_t)z * H_DIM * F_DIM
                          : Wu + (size_t)(z - 8) * H_DIM * F_DIM;
            C = F_DIM;
        } else {                       // Wd: R=512, C=1024 -> 8x16 tiles/z
            int u = v - 2048; z = 16 + (u >> 7); int rem = u & 127;
            c0 = (rem & 15) * 64; r0 = (rem >> 4) * 64;
            src = Wd + (size_t)(z - 16) * F_DIM * H_DIM;
            C = H_DIM;
        }
        int fr = tid >> 4, f4 = tid & 15;          // 16 rows/pass
#pragma unroll
        for (int p = 0; p < 4; ++p) {
            int row = p * 16 + fr;
            float4 v4 = *(const float4*)(src + (size_t)(r0 + row) * C + c0 + f4 * 4);
            tile[row][f4 * 4 + 0] = v4.x; tile[row][f4 * 4 + 1] = v4.y;
            tile[row][f4 * 4 + 2] = v4.z; tile[row][f4 * 4 + 3] = v4.w;
        }
        __syncthreads();
        int j = tid & 7, cl = tid >> 3;            // chunk-of-8-rows
#pragma unroll
        for (int p = 0; p < 2; ++p) {
            int c = cl + p * 32;
            bf16x8 w;
#pragma unroll
            for (int i = 0; i < 8; ++i) w[i] = (__bf16)tile[8 * j + i][c];
            if (z < 16) {
                int e = (z < 8) ? z : z - 8;
                int sel = (z < 8) ? 0 : 16;
                int f = c0 + c;
                int pp = ((f >> 4) << 5) + (f & 15) + sel;
                *(bf16x8*)&Wcat[(size_t)e * 2 * F_DIM * H_DIM + (size_t)pp * H_DIM + r0 + 8 * j] = w;
            } else {
                *(bf16x8*)&Wdt[(size_t)(z - 16) * H_DIM * F_DIM + (size_t)(c0 + c) * F_DIM + r0 + 8 * j] = w;
            }
        }
    }
}

// ---------------------------------------------------------------------------
// sort (8 blocks): each block redundantly computes histogram + scan, scatters
// ONE expert at deterministic offsets; block 0 emits tile worklist. No atomics.
// VERBATIM R12.
// ---------------------------------------------------------------------------
__global__ __launch_bounds__(256) void sort_kernel(
    const int* __restrict__ top_e, const float* __restrict__ top_w,
    int* __restrict__ perm, float* __restrict__ wts, int* __restrict__ tokslot,
    int* __restrict__ tile_e, int* __restrict__ tile_m0, int* __restrict__ tile_cnt,
    int* __restrict__ n_tiles)
{
    __shared__ int hist[N_EXP][256];
    __shared__ int ebase[N_EXP];
    int tid = threadIdx.x, myexp = blockIdx.x;
    int c[N_EXP];
#pragma unroll
    for (int e = 0; e < N_EXP; ++e) c[e] = 0;
#pragma unroll 4
    for (int i = 0; i < 32; ++i) {
        int ee = top_e[i * 256 + tid];
#pragma unroll
        for (int e = 0; e < N_EXP; ++e) c[e] += (ee == e);
    }
#pragma unroll
    for (int e = 0; e < N_EXP; ++e) hist[e][tid] = c[e];
    __syncthreads();
    for (int s = 1; s < 256; s <<= 1) {
        int v[N_EXP];
#pragma unroll
        for (int e = 0; e < N_EXP; ++e) v[e] = (tid >= s) ? hist[e][tid - s] : 0;
        __syncthreads();
#pragma unroll
        for (int e = 0; e < N_EXP; ++e) hist[e][tid] += v[e];
        __syncthreads();
    }
    if (tid == 0) {
        int o = 0, nt = 0;
        for (int e = 0; e < N_EXP; ++e) {
            ebase[e] = o;
            int ne = hist[e][255];
            if (myexp == 0) {
                for (int m0 = 0; m0 < ne; m0 += BM) {
                    tile_e[nt]   = e;
                    tile_m0[nt]  = o + m0;
                    tile_cnt[nt] = (ne - m0 < BM) ? (ne - m0) : BM;
                    ++nt;
                }
            }
            o += ne;
        }
        if (myexp == 0) *n_tiles = nt;
    }
    __syncthreads();
    int base = ebase[myexp] + hist[myexp][tid] - c[myexp];
#pragma unroll 4
    for (int i = 0; i < 32; ++i) {
        int a = i * 256 + tid;
        if (top_e[a] == myexp) {
            perm[base]   = a >> 1;
            wts[base]    = top_w[a];
            tokslot[a]   = base;
            ++base;
        }
    }
}

// ---------------------------------------------------------------------------
// m97-structure grouped GEMM for gate+up (packed N=1024), 128x128 tile, BK=64,
// single-buffer 33KB LDS, 3 blocks/CU, chunked bijective XCD swizzle.
// VERBATIM R12 champion (184.6us); R11/13/14/15/17 variants all lost.
// Epilogue: silu(gate)*up*combine_weight -> act (bf16).
// ---------------------------------------------------------------------------
__global__ __launch_bounds__(256, 3) void gateup_kernel(
    const __bf16* __restrict__ xb, const __bf16* __restrict__ Wcat,
    const int* __restrict__ perm, const float* __restrict__ wts,
    const int* __restrict__ tile_e, const int* __restrict__ tile_m0, const int* __restrict__ tile_cnt,
    const int* __restrict__ n_tiles, __bf16* __restrict__ act)
{
    int nat = (blockIdx.x & 7) * GRID_MT + (blockIdx.x >> 3);   // XCD-chunked
    int mt = nat >> 3;
    if (mt >= *n_tiles) return;
    int e = tile_e[mt], m0 = tile_m0[mt], mcnt = tile_cnt[mt];
    int n0 = (nat & 7) * BN;
    __shared__ __align__(16) __bf16 As[BM * BK];
    __shared__ __align__(16) __bf16 Bs[BN * BK];
    __shared__ int   rowtok[BM];
    __shared__ float roww[BM];
    int tid = threadIdx.x;
    if (tid < BM) {
        int slot = m0 + ((tid < mcnt) ? tid : 0);
        rowtok[tid] = perm[slot];
        roww[tid]   = wts[slot];
    }
    __syncthreads();
    int wave = tid >> 6, lane = tid & 63;
    int srow   = wave * 8 + (lane >> 3);
    int schunk = (((lane & 7) ^ ((lane >> 3) & 7))) * 8;
    const __bf16* We = Wcat + (size_t)e * (2 * F_DIM) * H_DIM;
    const __bf16* aptr[4];
    const __bf16* bptr[4];
#pragma unroll
    for (int j = 0; j < 4; ++j) {
        int r = j * 32 + srow;
        aptr[j] = xb + (size_t)rowtok[r] * H_DIM + schunk;
        bptr[j] = We + (size_t)(n0 + r) * H_DIM + schunk;
    }
    __bf16* aLds = As + wave * 512;
    __bf16* bLds = Bs + wave * 512;
    int wm = wave & 1, wn = wave >> 1;
    int quad = lane >> 4, l16 = lane & 15;
    f32x4 acc[4][4];
#pragma unroll
    for (int a = 0; a < 4; ++a)
#pragma unroll
        for (int b = 0; b < 4; ++b) acc[a][b] = (f32x4){0.f, 0.f, 0.f, 0.f};
    for (int k0 = 0; k0 < H_DIM; k0 += BK) {
#pragma unroll
        for (int j = 0; j < 4; ++j) {
            gl_lds16(aptr[j] + k0, aLds + j * 2048);
            gl_lds16(bptr[j] + k0, bLds + j * 2048);
        }
        __syncthreads();
#pragma unroll
        for (int s = 0; s < 2; ++s) {
            int sw = (((quad + s * 4) ^ (l16 & 7))) * 8;
            bf16x8 af[4], bf[4];
#pragma unroll
            for (int im = 0; im < 4; ++im)
                af[im] = *(const bf16x8*)&As[(wm * 64 + im * 16 + l16) * 64 + sw];
#pragma unroll
            for (int in = 0; in < 4; ++in)
                bf[in] = *(const bf16x8*)&Bs[(wn * 64 + in * 16 + l16) * 64 + sw];
#pragma unroll
            for (int im = 0; im < 4; ++im)
#pragma unroll
                for (int in = 0; in < 4; ++in)
                    acc[im][in] = MFMA16(af[im], bf[in], acc[im][in]);
        }
        __syncthreads();
    }
    int fbase = (n0 >> 1) + wn * 32;
#pragma unroll
    for (int im = 0; im < 4; ++im) {
#pragma unroll
        for (int ip = 0; ip < 2; ++ip) {
            f32x4 g = acc[im][ip * 2], u = acc[im][ip * 2 + 1];
            int fcol = fbase + ip * 16 + l16;
#pragma unroll
            for (int r = 0; r < 4; ++r) {
                int rl = wm * 64 + im * 16 + quad * 4 + r;
                if (rl < mcnt) {
                    float gv = g[r], uv = u[r];
                    float sg = gv / (1.f + __expf(-gv));
                    act[(size_t)(m0 + rl) * F_DIM + fcol] = (__bf16)(sg * uv * roww[rl]);
                }
            }
        }
    }
}

// ---------------------------------------------------------------------------
// m97-structure grouped down-proj: P[slot][h] = act[slot] @ Wd[e], bf16
// write-once stores. VERBATIM R12 champion.
// ---------------------------------------------------------------------------
__global__ __launch_bounds__(256, 3) void down_kernel(
    const __bf16* __restrict__ act, const __bf16* __restrict__ Wdt,
    const int* __restrict__ tile_e, const int* __restrict__ tile_m0, const int* __restrict__ tile_cnt,
    const int* __restrict__ n_tiles, __bf16* __restrict__ P)
{
    int nat = (blockIdx.x & 7) * GRID_MT + (blockIdx.x >> 3);   // XCD-chunked
    int mt = nat >> 3;
    if (mt >= *n_tiles) return;
    int e = tile_e[mt], m0 = tile_m0[mt], mcnt = tile_cnt[mt];
    int n0 = (nat & 7) * BN;
    __shared__ __align__(16) __bf16 As[BM * BK];
    __shared__ __align__(16) __bf16 Bs[BN * BK];
    int tid = threadIdx.x;
    int wave = tid >> 6, lane = tid & 63;
    int srow   = wave * 8 + (lane >> 3);
    int schunk = (((lane & 7) ^ ((lane >> 3) & 7))) * 8;
    const __bf16* Wd_e = Wdt + (size_t)e * H_DIM * F_DIM;
    const __bf16* aptr[4];
    const __bf16* bptr[4];
#pragma unroll
    for (int j = 0; j < 4; ++j) {
        int r = j * 32 + srow;
        int ar = m0 + ((r < mcnt) ? r : 0);
        aptr[j] = act  + (size_t)ar * F_DIM + schunk;
        bptr[j] = Wd_e + (size_t)(n0 + r) * F_DIM + schunk;
    }
    __bf16* aLds = As + wave * 512;
    __bf16* bLds = Bs + wave * 512;
    int wm = wave & 1, wn = wave >> 1;
    int quad = lane >> 4, l16 = lane & 15;
    f32x4 acc[4][4];
#pragma unroll
    for (int a = 0; a < 4; ++a)
#pragma unroll
        for (int b = 0; b < 4; ++b) acc[a][b] = (f32x4){0.f, 0.f, 0.f, 0.f};
    for (int k0 = 0; k0 < F_DIM; k0 += BK) {
#pragma unroll
        for (int j = 0; j < 4; ++j) {
            gl_lds16(aptr[j] + k0, aLds + j * 2048);
            gl_lds16(bptr[j] + k0, bLds + j * 2048);
        }
        __syncthreads();
#pragma unroll
        for (int s = 0; s < 2; ++s) {
            int sw = (((quad + s * 4) ^ (l16 & 7))) * 8;
            bf16x8 af[4], bf[4];
#pragma unroll
            for (int im = 0; im < 4; ++im)
                af[im] = *(const bf16x8*)&As[(wm * 64 + im * 16 + l16) * 64 + sw];
#pragma unroll
            for (int in = 0; in < 4; ++in)
                bf[in] = *(const bf16x8*)&Bs[(wn * 64 + in * 16 + l16) * 64 + sw];
#pragma unroll
            for (int im = 0; im < 4; ++im)
#pragma unroll
                for (int in = 0; in < 4; ++in)
                    acc[im][in] = MFMA16(af[im], bf[in], acc[im][in]);
        }
        __syncthreads();
    }
#pragma unroll
    for (int im = 0; im < 4; ++im) {
#pragma unroll
        for (int in = 0; in < 4; ++in) {
            int col = n0 + wn * 64 + in * 16 + l16;
#pragma unroll
            for (int r = 0; r < 4; ++r) {
                int rl = wm * 64 + im * 16 + quad * 4 + r;
                if (rl < mcnt)
                    P[(size_t)(m0 + rl) * H_DIM + col] = (__bf16)acc[im][in][r];
            }
        }
    }
}

// ---------------------------------------------------------------------------
// Combine: out[t] = P[slot1(t)] + P[slot2(t)] (fp32 accumulate). 1 wave/token,
// bf16x8 loads, f32x4 stores. VERBATIM R12.
// ---------------------------------------------------------------------------
__global__ __launch_bounds__(256) void combine_kernel(
    const __bf16* __restrict__ P, const int* __restrict__ tokslot,
    float* __restrict__ out)
{
    int wave = threadIdx.x >> 6, lane = threadIdx.x & 63;
    int t = blockIdx.x * 4 + wave;
    int s1 = tokslot[2 * t], s2 = tokslot[2 * t + 1];
    const bf16x8* p1 = (const bf16x8*)(P + (size_t)s1 * H_DIM);
    const bf16x8* p2 = (const bf16x8*)(P + (size_t)s2 * H_DIM);
    float* o = out + (size_t)t * H_DIM;
#pragma unroll
    for (int i = 0; i < 2; ++i) {
        int idx = i * 64 + lane;
        bf16x8 a = p1[idx], b = p2[idx];
        f32x4 lo, hi;
#pragma unroll
        for (int j = 0; j < 4; ++j) lo[j] = (float)a[j] + (float)b[j];
#pragma unroll
        for (int j = 0; j < 4; ++j) hi[j] = (float)a[4 + j] + (float)b[4 + j];
        *(f32x4*)(o + idx * 8)     = lo;
        *(f32x4*)(o + idx * 8 + 4) = hi;
    }
}

// ---------------------------------------------------------------------------
extern "C" void kernel_launch(void* const* d_in, const int* in_sizes, int n_in,
                              void* d_out, int out_size, void* d_ws, size_t ws_size,
                              hipStream_t stream)
{
    const float* x  = (const float*)d_in[0];
    const float* Wr = (const float*)d_in[1];
    const float* Wg = (const float*)d_in[2];
    const float* Wu = (const float*)d_in[3];
    const float* Wd = (const float*)d_in[4];
    float* out = (float*)d_out;

    char* ws = (char*)d_ws;
    size_t off = 0;
    auto carve = [&](size_t bytes) {
        char* p = ws + off;
        off = (off + bytes + 255) & ~(size_t)255;
        return p;
    };
    __bf16* xb   = (__bf16*)carve((size_t)T_TOK * H_DIM * 2);                 // 8 MB
    __bf16* Wcat = (__bf16*)carve((size_t)N_EXP * 2 * F_DIM * H_DIM * 2);     // 16 MB
    __bf16* Wdt  = (__bf16*)carve((size_t)N_EXP * H_DIM * F_DIM * 2);         // 8 MB
    __bf16* act  = (__bf16*)carve((size_t)N_ASSIGN * F_DIM * 2);              // 8 MB
    __bf16* P    = (__bf16*)carve((size_t)N_ASSIGN * H_DIM * 2);              // 16 MB
    int*   top_e = (int*)carve((size_t)T_TOK * 2 * sizeof(int));
    float* top_w = (float*)carve((size_t)T_TOK * 2 * sizeof(float));
    int*   perm  = (int*)carve((size_t)N_ASSIGN * sizeof(int));
    float* wts   = (float*)carve((size_t)N_ASSIGN * sizeof(float));
    int*  tokslot= (int*)carve((size_t)N_ASSIGN * sizeof(int));
    int*   tl_e  = (int*)carve(MAX_TILES * sizeof(int));
    int*   tl_m0 = (int*)carve(MAX_TILES * sizeof(int));
    int*   tl_cn = (int*)carve(MAX_TILES * sizeof(int));
    int*   n_til = (int*)carve(sizeof(int));

    prep_kernel<<<ROUTE_BLKS + TRU, 256, 0, stream>>>(
        Wg, Wu, Wd, Wcat, Wdt, x, Wr, xb, top_e, top_w);
    sort_kernel<<<N_EXP, 256, 0, stream>>>(
        top_e, top_w, perm, wts, tokslot, tl_e, tl_m0, tl_cn, n_til);
    gateup_kernel<<<GRID_MT * 8, 256, 0, stream>>>(
        xb, Wcat, perm, wts, tl_e, tl_m0, tl_cn, n_til, act);
    down_kernel<<<GRID_MT * 8, 256, 0, stream>>>(
        act, Wdt, tl_e, tl_m0, tl_cn, n_til, P);
    combine_kernel<<<T_TOK / 4, 256, 0, stream>>>(P, tokslot, out);
}